// Round 1
// baseline (268.754 us; speedup 1.0000x reference)
//
#include <hip/hip_runtime.h>
#include <math.h>

namespace {
constexpr int BB = 8;
constexpr int CH = 256;
constexpr int CQ = 32;
constexpr int NN = 4096;
}

typedef float f32x4 __attribute__((ext_vector_type(4)));
typedef short bf16x8 __attribute__((ext_vector_type(8)));
typedef unsigned short us8 __attribute__((ext_vector_type(8)));

#define MFMA16(a, b, c) __builtin_amdgcn_mfma_f32_16x16x32_bf16(a, b, c, 0, 0, 0)

__device__ __forceinline__ unsigned short f2bf(float x) {
    unsigned int u = __float_as_uint(x);
    u += 0x7fffu + ((u >> 16) & 1u);
    return (unsigned short)(u >> 16);
}
__device__ __forceinline__ float bf2f(unsigned short h) {
    return __uint_as_float(((unsigned int)h) << 16);
}
__device__ __forceinline__ void gload16(const void* g, void* l) {
    __builtin_amdgcn_global_load_lds(
        (const __attribute__((address_space(1))) unsigned int*)g,
        (__attribute__((address_space(3))) unsigned int*)l, 16, 0, 0);
}

// ---------------------------------------------------------------------------
// Kernel 0: split W (wq|wk|wv concat, 320x256) into bf16 hi/lo.
// ---------------------------------------------------------------------------
__global__ __launch_bounds__(256) void wsplit_kernel(
    const float* __restrict__ wq, const float* __restrict__ wk,
    const float* __restrict__ wv,
    unsigned short* __restrict__ wh, unsigned short* __restrict__ wl)
{
    int idx = blockIdx.x * 256 + threadIdx.x;   // 0..81919
    float v;
    if (idx < 8192)       v = wq[idx];
    else if (idx < 16384) v = wk[idx - 8192];
    else                  v = wv[idx - 16384];
    unsigned short hi = f2bf(v);
    wh[idx] = hi;
    wl[idx] = f2bf(v - bf2f(hi));
}

// ---------------------------------------------------------------------------
// Kernel 1: transpose+split X [b][256c][4096n] fp32 -> Xh/Xl [b][n][256c] bf16.
// Tile 64c x 64n per block; fully coalesced both sides via LDS.
// ---------------------------------------------------------------------------
__global__ __launch_bounds__(256) void transpose_kernel(
    const float* __restrict__ x,
    unsigned short* __restrict__ xh, unsigned short* __restrict__ xl)
{
    __shared__ float xf[64 * 68];                 // fp32 tile, padded rows
    __shared__ unsigned short hs[64 * 80];        // bf16 [n][64c] padded
    __shared__ unsigned short ls[64 * 80];
    const int t  = threadIdx.x;
    const int b  = blockIdx.x >> 8;
    const int tl = blockIdx.x & 255;
    const int c0 = (tl >> 6) * 64;
    const int n0 = (tl & 63) * 64;

    #pragma unroll
    for (int i = 0; i < 4; ++i) {
        int idx = i * 256 + t;
        int c = idx >> 4, nf = idx & 15;
        float4 v4 = *(const float4*)(x + ((size_t)(b * 256 + c0 + c)) * NN + n0 + nf * 4);
        *(float4*)(xf + c * 68 + nf * 4) = v4;
    }
    __syncthreads();

    const int n = t & 63;
    #pragma unroll
    for (int loop = 0; loop < 2; ++loop) {
        int chunk = (t >> 6) + 4 * loop;          // 0..7 (8 c's each)
        us8 h8, l8;
        #pragma unroll
        for (int j = 0; j < 8; ++j) {
            float v = xf[(chunk * 8 + j) * 68 + n];
            unsigned short hi = f2bf(v);
            h8[j] = hi;
            l8[j] = f2bf(v - bf2f(hi));
        }
        *(us8*)(hs + n * 80 + chunk * 8) = h8;
        *(us8*)(ls + n * 80 + chunk * 8) = l8;
    }
    __syncthreads();

    // copy-out: thread t -> row n=t>>2, 32B piece t&3; coalesced global writes
    {
        int rn = t >> 2, piece = t & 3;
        size_t grow = ((size_t)(b * NN + n0 + rn)) * 256 + c0 + piece * 16;
        *(us8*)(xh + grow)     = *(const us8*)(hs + rn * 80 + piece * 16);
        *(us8*)(xh + grow + 8) = *(const us8*)(hs + rn * 80 + piece * 16 + 8);
        *(us8*)(xl + grow)     = *(const us8*)(ls + rn * 80 + piece * 16);
        *(us8*)(xl + grow + 8) = *(const us8*)(ls + rn * 80 + piece * 16 + 8);
    }
}

// ---------------------------------------------------------------------------
// Kernel 2: proj GEMM via MFMA. D[och][pixel] = (Wh+Wl)(Xh+Xl) 3-MFMA split.
// Block = (b, 64-pixel tile). Wave w owns och-tiles w*5..w*5+4 (och 0..319:
// 0-31 q, 32-63 k, 64-319 v). Epilogue -> qh/ql/kh/kl [b][n][32], vt [b][c][n].
// ---------------------------------------------------------------------------
#define PJ_XL 32768
#define PJ_VE 16384
__global__ __launch_bounds__(256, 2) void proj_kernel(
    const unsigned short* __restrict__ xh, const unsigned short* __restrict__ xl,
    const unsigned short* __restrict__ wh, const unsigned short* __restrict__ wl,
    const float* __restrict__ bq, const float* __restrict__ bk,
    const float* __restrict__ bv,
    unsigned short* __restrict__ qh, unsigned short* __restrict__ ql,
    unsigned short* __restrict__ kh, unsigned short* __restrict__ kl,
    unsigned short* __restrict__ vt)
{
    __shared__ __align__(16) unsigned char smem[65536];
    const int t    = threadIdx.x;
    const int lane = t & 63;
    const int w    = t >> 6;
    const int l16  = lane & 15;
    const int quad = lane >> 4;
    const int b    = blockIdx.x >> 6;
    const int n0   = (blockIdx.x & 63) << 6;

    // stage Xh/Xl tile [64n][256c] with chunk-XOR swizzle (rows 512B)
    const unsigned char* xhB = (const unsigned char*)(xh + ((size_t)b * NN + n0) * 256);
    const unsigned char* xlB = (const unsigned char*)(xl + ((size_t)b * NN + n0) * 256);
    #pragma unroll
    for (int j = 0; j < 8; ++j) {
        int idx = j * 256 + t;
        int r = idx >> 5, cl = idx & 31;
        int cg = cl ^ (r & 7);
        gload16(xhB + (size_t)r * 512 + cg * 16, smem + idx * 16);
        gload16(xlB + (size_t)r * 512 + cg * 16, smem + PJ_XL + idx * 16);
    }
    __syncthreads();

    f32x4 acc[5][4] = {};
    #pragma unroll 1
    for (int kc = 0; kc < 8; ++kc) {
        bf16x8 ah[5], al[5];
        #pragma unroll
        for (int i = 0; i < 5; ++i) {
            int och = (w * 5 + i) * 16 + l16;
            ah[i] = *(const bf16x8*)(wh + och * 256 + kc * 32 + quad * 8);
            al[i] = *(const bf16x8*)(wl + och * 256 + kc * 32 + quad * 8);
        }
        #pragma unroll
        for (int nt = 0; nt < 4; ++nt) {
            int roff = (nt * 16 + l16) * 512 + (((kc * 4 + quad) ^ (l16 & 7)) * 16);
            bf16x8 bh = *(const bf16x8*)(smem + roff);
            bf16x8 bl = *(const bf16x8*)(smem + PJ_XL + roff);
            #pragma unroll
            for (int i = 0; i < 5; ++i) {
                acc[i][nt] = MFMA16(ah[i], bh, acc[i][nt]);
                acc[i][nt] = MFMA16(al[i], bh, acc[i][nt]);
                acc[i][nt] = MFMA16(ah[i], bl, acc[i][nt]);
            }
        }
    }
    __syncthreads();   // main-loop LDS reads done; alias epilogue regions

    // epilogue: bias add, split/pack into LDS, then coalesced copy-out
    #pragma unroll
    for (int i = 0; i < 5; ++i) {
        int tile = w * 5 + i;
        if (tile < 4) {  // q/k tiles (wave 0 only)
            #pragma unroll
            for (int r = 0; r < 4; ++r) {
                int och = tile * 16 + quad * 4 + r;
                float bias = (och < 32) ? bq[och] : bk[och - 32];
                int arr = (och < 32) ? 0 : 2;
                int oq = och & 31;
                #pragma unroll
                for (int nt = 0; nt < 4; ++nt) {
                    float val = acc[i][nt][r] + bias;
                    unsigned short hi = f2bf(val);
                    unsigned short lo = f2bf(val - bf2f(hi));
                    *(unsigned short*)(smem + arr * 4096 + (nt * 16 + l16) * 64 + oq * 2) = hi;
                    *(unsigned short*)(smem + (arr + 1) * 4096 + (nt * 16 + l16) * 64 + oq * 2) = lo;
                }
            }
        } else {          // v tiles
            #pragma unroll
            for (int r = 0; r < 4; ++r) {
                int voch = tile * 16 + quad * 4 + r - 64;
                float bias = bv[voch];
                #pragma unroll
                for (int nt = 0; nt < 4; ++nt) {
                    *(unsigned short*)(smem + PJ_VE + voch * 136 + (nt * 16 + l16) * 2)
                        = f2bf(acc[i][nt][r] + bias);
                }
            }
        }
    }
    __syncthreads();

    // copy-out q/k: 4 arrays x 64 rows x 64B
    {
        unsigned short* dsts[4] = { qh, ql, kh, kl };
        int arr = t >> 6, n = t & 63;
        unsigned short* dst = dsts[arr] + ((size_t)b * NN + n0 + n) * 32;
        #pragma unroll
        for (int i = 0; i < 4; ++i)
            *(us8*)(dst + i * 8) = *(const us8*)(smem + arr * 4096 + n * 64 + i * 16);
    }
    // copy-out v: 256 rows x 128B, 32B pieces for coalescing
    #pragma unroll
    for (int p = 0; p < 4; ++p) {
        int voch = p * 64 + (t >> 2), piece = t & 3;
        unsigned short* dst = vt + ((size_t)b * CH + voch) * NN + n0 + piece * 16;
        *(us8*)(dst)     = *(const us8*)(smem + PJ_VE + voch * 136 + piece * 32);
        *(us8*)(dst + 8) = *(const us8*)(smem + PJ_VE + voch * 136 + piece * 32 + 16);
    }
}

// ---------------------------------------------------------------------------
// Kernel 3: MFMA flash attention, single pass (no max: |e| << 88, fp32-safe).
// Block = (b via &7 XCD swizzle, 64-query tile), 4 waves.
// K/V are consumed straight from L2 (no intra-block reuse: E wave w owns 16
// keys, PV wave w owns 64 channels -> every element read exactly once per
// block). V frags issue at tile top, consumed after E+barrier (latency
// hidden). K frags prefetched one tile ahead in registers. Only P needs LDS
// (cross-wave); double-buffered -> single barrier per tile, no vmcnt drains.
// ---------------------------------------------------------------------------
#define A_P0 0          // P buffer 0: 64 rows x 144B = 9216
#define A_P1 9216       // P buffer 1
#define A_SM 18432      // 256 floats

__global__ __launch_bounds__(256, 2) void attn_kernel(
    const unsigned short* __restrict__ qh, const unsigned short* __restrict__ ql,
    const unsigned short* __restrict__ kh, const unsigned short* __restrict__ kl,
    const unsigned short* __restrict__ vt, const float* __restrict__ gptr,
    float* __restrict__ out)
{
    __shared__ __align__(16) unsigned char smem[19456];
    const int t    = threadIdx.x;
    const int lane = t & 63;
    const int w    = t >> 6;
    const int l16  = lane & 15;
    const int quad = lane >> 4;
    const int b    = blockIdx.x & 7;
    const int n0   = (blockIdx.x >> 3) << 6;

    // A-frags for all 4 query sub-tiles (hi/lo)
    bf16x8 qhA[4], qlA[4];
    #pragma unroll
    for (int qt = 0; qt < 4; ++qt) {
        size_t row = (size_t)b * NN + n0 + qt * 16 + l16;
        qhA[qt] = *(const bf16x8*)(qh + row * 32 + quad * 8);
        qlA[qt] = *(const bf16x8*)(ql + row * 32 + quad * 8);
    }

    // per-lane V base pointers: channel = w*64 + ct*16 + l16, key-chunk quad*8
    const unsigned short* vbase[4];
    #pragma unroll
    for (int ct = 0; ct < 4; ++ct)
        vbase[ct] = vt + (size_t)b * CH * NN
                       + (size_t)(w * 64 + ct * 16 + l16) * NN + quad * 8;
    // per-lane K base pointers: key = w*16 + l16, channel-chunk quad*8
    const unsigned short* khbase = kh + ((size_t)b * NN + w * 16 + l16) * 32 + quad * 8;
    const unsigned short* klbase = kl + ((size_t)b * NN + w * 16 + l16) * 32 + quad * 8;

    f32x4 acc[4][4] = {};
    float S[4][4] = {};

    // prologue: K frags for tile 0
    bf16x8 kch = *(const bf16x8*)(khbase);
    bf16x8 kcl = *(const bf16x8*)(klbase);

    #pragma unroll 1
    for (int tile = 0; tile < 64; ++tile) {
        const int m0 = tile * 64;
        const int m1 = ((tile + 1) & 63) * 64;   // wrap: last-iter load harmless

        // issue V loads for THIS tile (consumed after E + barrier)
        bf16x8 vr0[4], vr1[4];
        #pragma unroll
        for (int ct = 0; ct < 4; ++ct) {
            vr0[ct] = *(const bf16x8*)(vbase[ct] + m0);
            vr1[ct] = *(const bf16x8*)(vbase[ct] + m0 + 32);
        }
        // issue K loads for NEXT tile (consumed next iteration)
        bf16x8 knh = *(const bf16x8*)(khbase + (size_t)m1 * 32);
        bf16x8 knl = *(const bf16x8*)(klbase + (size_t)m1 * 32);

        // E: wave w's 16 keys x all 64 queries, from registers
        unsigned char* P = smem + ((tile & 1) ? A_P1 : A_P0);
        #pragma unroll
        for (int qt = 0; qt < 4; ++qt) {
            f32x4 e = { 0.f, 0.f, 0.f, 0.f };
            e = MFMA16(qhA[qt], kch, e);
            e = MFMA16(qlA[qt], kch, e);
            e = MFMA16(qhA[qt], kcl, e);
            #pragma unroll
            for (int r = 0; r < 4; ++r) {
                float p = __expf(e[r]);
                unsigned short pb = f2bf(p);
                S[qt][r] += bf2f(pb);
                *(unsigned short*)(P + (qt * 16 + quad * 4 + r) * 144
                                     + (w * 16 + l16) * 2) = pb;
            }
        }
        __syncthreads();   // P ready (only barrier in the loop)

        // PV: A = P rows (LDS), B = V frags (registers)
        #pragma unroll
        for (int ks = 0; ks < 2; ++ks) {
            bf16x8 af[4];
            #pragma unroll
            for (int qt = 0; qt < 4; ++qt)
                af[qt] = *(const bf16x8*)(P + (qt * 16 + l16) * 144
                                            + ks * 64 + quad * 16);
            #pragma unroll
            for (int qt = 0; qt < 4; ++qt) {
                #pragma unroll
                for (int ct = 0; ct < 4; ++ct)
                    acc[qt][ct] = MFMA16(af[qt], ks ? vr1[ct] : vr0[ct],
                                         acc[qt][ct]);
            }
        }
        kch = knh;
        kcl = knl;
    }

    // reduce S over key-lanes, then across waves via LDS
    #pragma unroll
    for (int mask = 1; mask <= 8; mask <<= 1)
        #pragma unroll
        for (int qt = 0; qt < 4; ++qt)
            #pragma unroll
            for (int r = 0; r < 4; ++r)
                S[qt][r] += __shfl_xor(S[qt][r], mask);
    float* SM = (float*)(smem + A_SM);
    if (l16 == 0) {
        #pragma unroll
        for (int qt = 0; qt < 4; ++qt)
            #pragma unroll
            for (int r = 0; r < 4; ++r)
                SM[w * 64 + qt * 16 + quad * 4 + r] = S[qt][r];
    }
    __syncthreads();

    const float g1 = 1.f + gptr[0];
    float* ob = out + (size_t)b * CH * NN;
    #pragma unroll
    for (int qt = 0; qt < 4; ++qt) {
        float is[4];
        #pragma unroll
        for (int r = 0; r < 4; ++r) {
            int qi = qt * 16 + quad * 4 + r;
            float Sf = SM[qi] + SM[64 + qi] + SM[128 + qi] + SM[192 + qi];
            is[r] = g1 / Sf;
        }
        #pragma unroll
        for (int ct = 0; ct < 4; ++ct) {
            float4 o4;
            o4.x = floorf(acc[qt][ct][0] * is[0] * 256.f) * 0.00390625f;
            o4.y = floorf(acc[qt][ct][1] * is[1] * 256.f) * 0.00390625f;
            o4.z = floorf(acc[qt][ct][2] * is[2] * 256.f) * 0.00390625f;
            o4.w = floorf(acc[qt][ct][3] * is[3] * 256.f) * 0.00390625f;
            *(float4*)(ob + (size_t)(w * 64 + ct * 16 + l16) * NN
                          + n0 + qt * 16 + quad * 4) = o4;
        }
    }
}

// ---------------------------------------------------------------------------
extern "C" void kernel_launch(void* const* d_in, const int* in_sizes, int n_in,
                              void* d_out, int out_size, void* d_ws, size_t ws_size,
                              hipStream_t stream) {
    const float* x  = (const float*)d_in[0];
    const float* wq = (const float*)d_in[1];
    const float* bq = (const float*)d_in[2];
    const float* wk = (const float*)d_in[3];
    const float* bk = (const float*)d_in[4];
    const float* wv = (const float*)d_in[5];
    const float* bv = (const float*)d_in[6];
    const float* gm = (const float*)d_in[7];
    float* out = (float*)d_out;

    unsigned short* ws = (unsigned short*)d_ws;
    const size_t XSZ = (size_t)BB * NN * 256;   // 8,388,608
    const size_t WSZ = 320 * 256;               // 81,920
    const size_t QSZ = (size_t)BB * NN * 32;    // 1,048,576
    unsigned short* xh = ws;
    unsigned short* xl = xh + XSZ;
    unsigned short* wh = xl + XSZ;
    unsigned short* wl = wh + WSZ;
    unsigned short* qh = wl + WSZ;
    unsigned short* ql = qh + QSZ;
    unsigned short* kh = ql + QSZ;
    unsigned short* kl = kh + QSZ;
    unsigned short* vt = kl + QSZ;

    wsplit_kernel<<<320, 256, 0, stream>>>(wq, wk, wv, wh, wl);
    transpose_kernel<<<2048, 256, 0, stream>>>(x, xh, xl);
    proj_kernel<<<512, 256, 0, stream>>>(xh, xl, wh, wl, bq, bk, bv,
                                         qh, ql, kh, kl, vt);
    attn_kernel<<<512, 256, 0, stream>>>(qh, ql, kh, kl, vt, gm, out);
}

// Round 2
// 246.238 us; speedup vs baseline: 1.0914x; 1.0914x over previous
//
#include <hip/hip_runtime.h>
#include <math.h>

namespace {
constexpr int BB = 8;
constexpr int CH = 256;
constexpr int CQ = 32;
constexpr int NN = 4096;
}

typedef float f32x4 __attribute__((ext_vector_type(4)));
typedef short bf16x8 __attribute__((ext_vector_type(8)));
typedef unsigned short us8 __attribute__((ext_vector_type(8)));

#define MFMA16(a, b, c) __builtin_amdgcn_mfma_f32_16x16x32_bf16(a, b, c, 0, 0, 0)

__device__ __forceinline__ unsigned short f2bf(float x) {
    unsigned int u = __float_as_uint(x);
    u += 0x7fffu + ((u >> 16) & 1u);
    return (unsigned short)(u >> 16);
}
__device__ __forceinline__ float bf2f(unsigned short h) {
    return __uint_as_float(((unsigned int)h) << 16);
}
__device__ __forceinline__ void gload16(const void* g, void* l) {
    __builtin_amdgcn_global_load_lds(
        (const __attribute__((address_space(1))) unsigned int*)g,
        (__attribute__((address_space(3))) unsigned int*)l, 16, 0, 0);
}

// ---------------------------------------------------------------------------
// Kernel 0: split W (wq|wk|wv concat, 320x256) into bf16 hi/lo.
// ---------------------------------------------------------------------------
__global__ __launch_bounds__(256) void wsplit_kernel(
    const float* __restrict__ wq, const float* __restrict__ wk,
    const float* __restrict__ wv,
    unsigned short* __restrict__ wh, unsigned short* __restrict__ wl)
{
    int idx = blockIdx.x * 256 + threadIdx.x;   // 0..81919
    float v;
    if (idx < 8192)       v = wq[idx];
    else if (idx < 16384) v = wk[idx - 8192];
    else                  v = wv[idx - 16384];
    unsigned short hi = f2bf(v);
    wh[idx] = hi;
    wl[idx] = f2bf(v - bf2f(hi));
}

// ---------------------------------------------------------------------------
// Kernel 1: transpose+split X [b][256c][4096n] fp32 -> Xh/Xl [b][n][256c] bf16.
// Tile 64c x 64n per block; fully coalesced both sides via LDS.
// ---------------------------------------------------------------------------
__global__ __launch_bounds__(256) void transpose_kernel(
    const float* __restrict__ x,
    unsigned short* __restrict__ xh, unsigned short* __restrict__ xl)
{
    __shared__ float xf[64 * 68];                 // fp32 tile, padded rows
    __shared__ unsigned short hs[64 * 80];        // bf16 [n][64c] padded
    __shared__ unsigned short ls[64 * 80];
    const int t  = threadIdx.x;
    const int b  = blockIdx.x >> 8;
    const int tl = blockIdx.x & 255;
    const int c0 = (tl >> 6) * 64;
    const int n0 = (tl & 63) * 64;

    #pragma unroll
    for (int i = 0; i < 4; ++i) {
        int idx = i * 256 + t;
        int c = idx >> 4, nf = idx & 15;
        float4 v4 = *(const float4*)(x + ((size_t)(b * 256 + c0 + c)) * NN + n0 + nf * 4);
        *(float4*)(xf + c * 68 + nf * 4) = v4;
    }
    __syncthreads();

    const int n = t & 63;
    #pragma unroll
    for (int loop = 0; loop < 2; ++loop) {
        int chunk = (t >> 6) + 4 * loop;          // 0..7 (8 c's each)
        us8 h8, l8;
        #pragma unroll
        for (int j = 0; j < 8; ++j) {
            float v = xf[(chunk * 8 + j) * 68 + n];
            unsigned short hi = f2bf(v);
            h8[j] = hi;
            l8[j] = f2bf(v - bf2f(hi));
        }
        *(us8*)(hs + n * 80 + chunk * 8) = h8;
        *(us8*)(ls + n * 80 + chunk * 8) = l8;
    }
    __syncthreads();

    // copy-out: thread t -> row n=t>>2, 32B piece t&3; coalesced global writes
    {
        int rn = t >> 2, piece = t & 3;
        size_t grow = ((size_t)(b * NN + n0 + rn)) * 256 + c0 + piece * 16;
        *(us8*)(xh + grow)     = *(const us8*)(hs + rn * 80 + piece * 16);
        *(us8*)(xh + grow + 8) = *(const us8*)(hs + rn * 80 + piece * 16 + 8);
        *(us8*)(xl + grow)     = *(const us8*)(ls + rn * 80 + piece * 16);
        *(us8*)(xl + grow + 8) = *(const us8*)(ls + rn * 80 + piece * 16 + 8);
    }
}

// ---------------------------------------------------------------------------
// Kernel 2: proj GEMM via MFMA. D[och][pixel] = (Wh+Wl)(Xh+Xl) 3-MFMA split.
// Block = (b, 64-pixel tile). Wave w owns och-tiles w*5..w*5+4 (och 0..319:
// 0-31 q, 32-63 k, 64-319 v). Epilogue -> qh/ql/kh/kl [b][n][32], vt [b][c][n].
// ---------------------------------------------------------------------------
#define PJ_XL 32768
#define PJ_VE 16384
__global__ __launch_bounds__(256, 2) void proj_kernel(
    const unsigned short* __restrict__ xh, const unsigned short* __restrict__ xl,
    const unsigned short* __restrict__ wh, const unsigned short* __restrict__ wl,
    const float* __restrict__ bq, const float* __restrict__ bk,
    const float* __restrict__ bv,
    unsigned short* __restrict__ qh, unsigned short* __restrict__ ql,
    unsigned short* __restrict__ kh, unsigned short* __restrict__ kl,
    unsigned short* __restrict__ vt)
{
    __shared__ __align__(16) unsigned char smem[65536];
    const int t    = threadIdx.x;
    const int lane = t & 63;
    const int w    = t >> 6;
    const int l16  = lane & 15;
    const int quad = lane >> 4;
    const int b    = blockIdx.x >> 6;
    const int n0   = (blockIdx.x & 63) << 6;

    // stage Xh/Xl tile [64n][256c] with chunk-XOR swizzle (rows 512B)
    const unsigned char* xhB = (const unsigned char*)(xh + ((size_t)b * NN + n0) * 256);
    const unsigned char* xlB = (const unsigned char*)(xl + ((size_t)b * NN + n0) * 256);
    #pragma unroll
    for (int j = 0; j < 8; ++j) {
        int idx = j * 256 + t;
        int r = idx >> 5, cl = idx & 31;
        int cg = cl ^ (r & 7);
        gload16(xhB + (size_t)r * 512 + cg * 16, smem + idx * 16);
        gload16(xlB + (size_t)r * 512 + cg * 16, smem + PJ_XL + idx * 16);
    }
    __syncthreads();

    f32x4 acc[5][4] = {};
    #pragma unroll 1
    for (int kc = 0; kc < 8; ++kc) {
        bf16x8 ah[5], al[5];
        #pragma unroll
        for (int i = 0; i < 5; ++i) {
            int och = (w * 5 + i) * 16 + l16;
            ah[i] = *(const bf16x8*)(wh + och * 256 + kc * 32 + quad * 8);
            al[i] = *(const bf16x8*)(wl + och * 256 + kc * 32 + quad * 8);
        }
        #pragma unroll
        for (int nt = 0; nt < 4; ++nt) {
            int roff = (nt * 16 + l16) * 512 + (((kc * 4 + quad) ^ (l16 & 7)) * 16);
            bf16x8 bh = *(const bf16x8*)(smem + roff);
            bf16x8 bl = *(const bf16x8*)(smem + PJ_XL + roff);
            #pragma unroll
            for (int i = 0; i < 5; ++i) {
                acc[i][nt] = MFMA16(ah[i], bh, acc[i][nt]);
                acc[i][nt] = MFMA16(al[i], bh, acc[i][nt]);
                acc[i][nt] = MFMA16(ah[i], bl, acc[i][nt]);
            }
        }
    }
    __syncthreads();   // main-loop LDS reads done; alias epilogue regions

    // epilogue: bias add, split/pack into LDS, then coalesced copy-out
    #pragma unroll
    for (int i = 0; i < 5; ++i) {
        int tile = w * 5 + i;
        if (tile < 4) {  // q/k tiles (wave 0 only)
            #pragma unroll
            for (int r = 0; r < 4; ++r) {
                int och = tile * 16 + quad * 4 + r;
                float bias = (och < 32) ? bq[och] : bk[och - 32];
                int arr = (och < 32) ? 0 : 2;
                int oq = och & 31;
                #pragma unroll
                for (int nt = 0; nt < 4; ++nt) {
                    float val = acc[i][nt][r] + bias;
                    unsigned short hi = f2bf(val);
                    unsigned short lo = f2bf(val - bf2f(hi));
                    *(unsigned short*)(smem + arr * 4096 + (nt * 16 + l16) * 64 + oq * 2) = hi;
                    *(unsigned short*)(smem + (arr + 1) * 4096 + (nt * 16 + l16) * 64 + oq * 2) = lo;
                }
            }
        } else {          // v tiles
            #pragma unroll
            for (int r = 0; r < 4; ++r) {
                int voch = tile * 16 + quad * 4 + r - 64;
                float bias = bv[voch];
                #pragma unroll
                for (int nt = 0; nt < 4; ++nt) {
                    *(unsigned short*)(smem + PJ_VE + voch * 136 + (nt * 16 + l16) * 2)
                        = f2bf(acc[i][nt][r] + bias);
                }
            }
        }
    }
    __syncthreads();

    // copy-out q/k: 4 arrays x 64 rows x 64B
    {
        unsigned short* dsts[4] = { qh, ql, kh, kl };
        int arr = t >> 6, n = t & 63;
        unsigned short* dst = dsts[arr] + ((size_t)b * NN + n0 + n) * 32;
        #pragma unroll
        for (int i = 0; i < 4; ++i)
            *(us8*)(dst + i * 8) = *(const us8*)(smem + arr * 4096 + n * 64 + i * 16);
    }
    // copy-out v: 256 rows x 128B, 32B pieces for coalescing
    #pragma unroll
    for (int p = 0; p < 4; ++p) {
        int voch = p * 64 + (t >> 2), piece = t & 3;
        unsigned short* dst = vt + ((size_t)b * CH + voch) * NN + n0 + piece * 16;
        *(us8*)(dst)     = *(const us8*)(smem + PJ_VE + voch * 136 + piece * 32);
        *(us8*)(dst + 8) = *(const us8*)(smem + PJ_VE + voch * 136 + piece * 32 + 16);
    }
}

// ---------------------------------------------------------------------------
// Kernel 3: MFMA flash attention, single pass (no max: |e| << 88, fp32-safe).
// Block = (b via &7 XCD swizzle, 64-query tile), 4 waves.
// Schedule: ONE barrier per tile. All VMEM (V staging via gload_lds into the
// alternate LDS buffer + next K into regs) issues immediately after the
// barrier and is consumed a full phase (~PV+E) later, so the vmcnt(0) drain
// inside __syncthreads costs ~nothing. V double-buffered (2x32KB), P
// double-buffered (2x8KB, stride 128 + chunk-XOR swizzle -> ~2-way max
// conflicts). LDS = 80KB exactly -> 2 blocks/CU. SM aliases V0 (dead after
// loop; last stage guarded).
// ---------------------------------------------------------------------------
#define A_P0 0          // P buffer 0: 64 rows x 128B
#define A_P1 8192       // P buffer 1
#define A_V0 16384      // V buffer 0: 256ch x 128B
#define A_V1 49152      // V buffer 1
#define A_SM 16384      // 256 floats, aliases V0 (post-loop only)

__global__ __launch_bounds__(256, 2) void attn_kernel(
    const unsigned short* __restrict__ qh, const unsigned short* __restrict__ ql,
    const unsigned short* __restrict__ kh, const unsigned short* __restrict__ kl,
    const unsigned short* __restrict__ vt, const float* __restrict__ gptr,
    float* __restrict__ out)
{
    __shared__ __align__(16) unsigned char smem[81920];
    const int t    = threadIdx.x;
    const int lane = t & 63;
    const int w    = t >> 6;
    const int l16  = lane & 15;
    const int quad = lane >> 4;
    const int b    = blockIdx.x & 7;
    const int n0   = (blockIdx.x >> 3) << 6;

    // A-frags for all 4 query sub-tiles (hi/lo)
    bf16x8 qhA[4], qlA[4];
    #pragma unroll
    for (int qt = 0; qt < 4; ++qt) {
        size_t row = (size_t)b * NN + n0 + qt * 16 + l16;
        qhA[qt] = *(const bf16x8*)(qh + row * 32 + quad * 8);
        qlA[qt] = *(const bf16x8*)(ql + row * 32 + quad * 8);
    }

    const unsigned short* khbase = kh + ((size_t)b * NN + w * 16 + l16) * 32 + quad * 8;
    const unsigned short* klbase = kl + ((size_t)b * NN + w * 16 + l16) * 32 + quad * 8;
    const unsigned char*  vtB    = (const unsigned char*)(vt + (size_t)b * CH * NN);

    f32x4 acc[4][4] = {};
    float S[4][4] = {};

    // prologue: K_0 regs first (oldest VMEM -> compiler waits vmcnt(8), not 0)
    bf16x8 kch = *(const bf16x8*)(khbase);
    bf16x8 kcl = *(const bf16x8*)(klbase);
    // then stage V_0 into V0 (chunk-XOR swizzle on 128B rows)
    #pragma unroll
    for (int j = 0; j < 8; ++j) {
        int idx = j * 256 + t;
        int r = idx >> 3, cl = idx & 7;
        int cg = cl ^ (r & 7);
        gload16(vtB + (size_t)r * 8192 + cg * 16, smem + A_V0 + idx * 16);
    }

    #pragma unroll 1
    for (int tile = 0; tile < 64; ++tile) {
        // ---- E phase: wave w's 16 keys x all 64 queries (regs only) ----
        unsigned char* P = smem + ((tile & 1) ? A_P1 : A_P0);
        const int key = w * 16 + l16;
        #pragma unroll
        for (int qt = 0; qt < 4; ++qt) {
            f32x4 e = { 0.f, 0.f, 0.f, 0.f };
            e = MFMA16(qhA[qt], kch, e);
            e = MFMA16(qlA[qt], kch, e);
            e = MFMA16(qhA[qt], kcl, e);
            #pragma unroll
            for (int r = 0; r < 4; ++r) {
                float p = __expf(e[r]);
                unsigned short pb = f2bf(p);
                S[qt][r] += bf2f(pb);
                int row = qt * 16 + quad * 4 + r;
                *(unsigned short*)(P + row * 128
                                     + ((((key >> 3) ^ (row & 7)) << 4)
                                        | ((key & 7) << 1))) = pb;
            }
        }

        __syncthreads();   // P_tile + V_tile ready; prev PV reads drained

        // ---- issue next-tile VMEM (consumed after NEXT barrier) ----
        const int m1 = ((tile + 1) & 63) * 64;
        bf16x8 knh = *(const bf16x8*)(khbase + (size_t)m1 * 32);
        bf16x8 knl = *(const bf16x8*)(klbase + (size_t)m1 * 32);
        if (tile < 63) {
            unsigned char* vdst = smem + ((tile & 1) ? A_V0 : A_V1);
            const unsigned char* vsrc = vtB + (size_t)m1 * 2;
            #pragma unroll
            for (int j = 0; j < 8; ++j) {
                int idx = j * 256 + t;
                int r = idx >> 3, cl = idx & 7;
                int cg = cl ^ (r & 7);
                gload16(vsrc + (size_t)r * 8192 + cg * 16, vdst + idx * 16);
            }
        }

        // ---- PV phase: A = P rows (LDS), B = V frags (LDS, swizzled) ----
        const unsigned char* VB = smem + ((tile & 1) ? A_V1 : A_V0);
        #pragma unroll
        for (int ks = 0; ks < 2; ++ks) {
            bf16x8 af[4], bfr[4];
            #pragma unroll
            for (int qt = 0; qt < 4; ++qt) {
                int row = qt * 16 + l16;
                af[qt] = *(const bf16x8*)(P + row * 128
                                            + (((ks * 4 + quad) ^ (row & 7)) << 4));
            }
            #pragma unroll
            for (int ct = 0; ct < 4; ++ct) {
                int vrow = w * 64 + ct * 16 + l16;
                int ch = (ks * 4 + quad) ^ (l16 & 7);
                bfr[ct] = *(const bf16x8*)(VB + vrow * 128 + ch * 16);
            }
            __builtin_amdgcn_s_setprio(1);
            #pragma unroll
            for (int qt = 0; qt < 4; ++qt)
                #pragma unroll
                for (int ct = 0; ct < 4; ++ct)
                    acc[qt][ct] = MFMA16(af[qt], bfr[ct], acc[qt][ct]);
            __builtin_amdgcn_s_setprio(0);
        }
        kch = knh;
        kcl = knl;
    }

    // reduce S over key-lanes, then across waves via LDS
    #pragma unroll
    for (int mask = 1; mask <= 8; mask <<= 1)
        #pragma unroll
        for (int qt = 0; qt < 4; ++qt)
            #pragma unroll
            for (int r = 0; r < 4; ++r)
                S[qt][r] += __shfl_xor(S[qt][r], mask);
    float* SM = (float*)(smem + A_SM);
    if (l16 == 0) {
        #pragma unroll
        for (int qt = 0; qt < 4; ++qt)
            #pragma unroll
            for (int r = 0; r < 4; ++r)
                SM[w * 64 + qt * 16 + quad * 4 + r] = S[qt][r];
    }
    __syncthreads();

    const float g1 = 1.f + gptr[0];
    float* ob = out + (size_t)b * CH * NN;
    #pragma unroll
    for (int qt = 0; qt < 4; ++qt) {
        float is[4];
        #pragma unroll
        for (int r = 0; r < 4; ++r) {
            int qi = qt * 16 + quad * 4 + r;
            float Sf = SM[qi] + SM[64 + qi] + SM[128 + qi] + SM[192 + qi];
            is[r] = g1 / Sf;
        }
        #pragma unroll
        for (int ct = 0; ct < 4; ++ct) {
            float4 o4;
            o4.x = floorf(acc[qt][ct][0] * is[0] * 256.f) * 0.00390625f;
            o4.y = floorf(acc[qt][ct][1] * is[1] * 256.f) * 0.00390625f;
            o4.z = floorf(acc[qt][ct][2] * is[2] * 256.f) * 0.00390625f;
            o4.w = floorf(acc[qt][ct][3] * is[3] * 256.f) * 0.00390625f;
            *(float4*)(ob + (size_t)(w * 64 + ct * 16 + l16) * NN
                          + n0 + qt * 16 + quad * 4) = o4;
        }
    }
}

// ---------------------------------------------------------------------------
extern "C" void kernel_launch(void* const* d_in, const int* in_sizes, int n_in,
                              void* d_out, int out_size, void* d_ws, size_t ws_size,
                              hipStream_t stream) {
    const float* x  = (const float*)d_in[0];
    const float* wq = (const float*)d_in[1];
    const float* bq = (const float*)d_in[2];
    const float* wk = (const float*)d_in[3];
    const float* bk = (const float*)d_in[4];
    const float* wv = (const float*)d_in[5];
    const float* bv = (const float*)d_in[6];
    const float* gm = (const float*)d_in[7];
    float* out = (float*)d_out;

    unsigned short* ws = (unsigned short*)d_ws;
    const size_t XSZ = (size_t)BB * NN * 256;   // 8,388,608
    const size_t WSZ = 320 * 256;               // 81,920
    const size_t QSZ = (size_t)BB * NN * 32;    // 1,048,576
    unsigned short* xh = ws;
    unsigned short* xl = xh + XSZ;
    unsigned short* wh = xl + XSZ;
    unsigned short* wl = wh + WSZ;
    unsigned short* qh = wl + WSZ;
    unsigned short* ql = qh + QSZ;
    unsigned short* kh = ql + QSZ;
    unsigned short* kl = kh + QSZ;
    unsigned short* vt = kl + QSZ;

    wsplit_kernel<<<320, 256, 0, stream>>>(wq, wk, wv, wh, wl);
    transpose_kernel<<<2048, 256, 0, stream>>>(x, xh, xl);
    proj_kernel<<<512, 256, 0, stream>>>(xh, xl, wh, wl, bq, bk, bv,
                                         qh, ql, kh, kl, vt);
    attn_kernel<<<512, 256, 0, stream>>>(qh, ql, kh, kl, vt, gm, out);
}